// Round 16
// baseline (220.015 us; speedup 1.0000x reference)
//
#include <hip/hip_runtime.h>
#include <cstdint>
#include <cstddef>

#define DEV __device__ __forceinline__

// ---------------- problem constants ----------------
constexpr size_t W_TOT = 131712;
constexpr size_t OFF_W1 = 0;       // [128][256]
constexpr size_t OFF_B1 = 32768;   // [256]
constexpr size_t OFF_W2 = 33024;   // [256][256]
constexpr size_t OFF_B2 = 98560;   // [256]
constexpr size_t OFF_W3 = 98816;   // [256][128]
constexpr size_t OFF_B3 = 131584;  // [128]

constexpr int OPS = 272;           // LDS activation row stride

// ---------------- workspace layout (floats) ----------------
constexpr size_t P_LOSS = 0;                    // [4][256]
constexpr size_t P_WA   = 1024;                 // [8][32]
constexpr size_t P_WU   = 1280;                 // [8][32]
constexpr size_t P_FT   = 1536;                 // [8]
constexpr size_t P_HP   = 2048;                 // [256][4]
constexpr size_t P_H2PI = 4096;                 // [256][128]
constexpr size_t P_ENC  = P_H2PI + 32768;       // [256][128]
constexpr size_t P_DGS  = P_ENC + 32768;        // [256][128]
constexpr size_t P_KEYS = P_DGS + 32768;        // [256][128]
constexpr size_t P_VALS = P_KEYS + 32768;       // [256][128]
constexpr size_t P_D3   = P_VALS + 32768;       // [256][128]
constexpr size_t P_H1   = P_D3 + 32768;         // [256][256]
constexpr size_t P_H2   = P_H1 + 65536;         // [256][256]
constexpr size_t P_D1   = P_H2 + 65536;         // [256][256]
constexpr size_t P_D2   = P_D1 + 65536;         // [256][256]
constexpr size_t P_STRUCT = P_D2 + 65536;       // [256][128]
constexpr size_t P_TRANS  = P_STRUCT + 32768;   // [256][16384]

DEV float sigm(float x) { return 1.f / (1.f + expf(-x)); }

// 512-thread WG sum; returns total to ALL threads.
DEV float wgsum512(float v, float* red) {
#pragma unroll
  for (int s = 32; s > 0; s >>= 1) v += __shfl_xor(v, s);
  if ((threadIdx.x & 63) == 0) red[threadIdx.x >> 6] = v;
  __syncthreads();
  float t = 0.f;
#pragma unroll
  for (int w = 0; w < 8; ++w) t += red[w];
  __syncthreads();
  return t;
}

// =========================================================================
// dense512: 512 threads, one float4 col-group/thread, 8-deep ping-pong,
// cross-thread split-K, LDS combine.
// =========================================================================
template<int K, int OUT, int ROWS>
DEV void dense512(const float* __restrict__ W, const float* __restrict__ bias,
                  const float* in, int ips, float* out, int ops, int relu,
                  float* scr)
{
  constexpr int OUTG = OUT / 4;            // float4 col-groups
  constexpr int NSEG = 512 / OUTG;         // cross-thread K segments
  constexpr int KS   = K / NSEG;           // K elems per segment
  constexpr int NG   = KS / 8;             // 8-deep windows (>=1)
  static_assert(K % NSEG == 0 && KS % 8 == 0 && NG >= 1, "bad shape");
  const int tid = (int)threadIdx.x;
  const int c   = tid & (OUTG - 1);
  const int seg = tid / OUTG;
  const int k0  = seg * KS;
  const float4* W4 = reinterpret_cast<const float4*>(W);
  float4 w0[8], w1[8];
  float acc[ROWS][4];
#pragma unroll
  for (int r = 0; r < ROWS; ++r) {
    acc[r][0] = 0.f; acc[r][1] = 0.f; acc[r][2] = 0.f; acc[r][3] = 0.f;
  }
#pragma unroll
  for (int u = 0; u < 8; ++u) w0[u] = W4[(size_t)(k0 + u) * OUTG + c];
#pragma unroll
  for (int t = 1; t <= NG; ++t) {
    if (t < NG) {
#pragma unroll
      for (int u = 0; u < 8; ++u) w1[u] = W4[(size_t)(k0 + t * 8 + u) * OUTG + c];
    }
#pragma unroll
    for (int u = 0; u < 8; ++u) {
      const int kk = k0 + (t - 1) * 8 + u;
#pragma unroll
      for (int r = 0; r < ROWS; ++r) {
        const float x = in[r * ips + kk];
        acc[r][0] = fmaf(x, w0[u].x, acc[r][0]);
        acc[r][1] = fmaf(x, w0[u].y, acc[r][1]);
        acc[r][2] = fmaf(x, w0[u].z, acc[r][2]);
        acc[r][3] = fmaf(x, w0[u].w, acc[r][3]);
      }
    }
    if (t < NG) {
#pragma unroll
      for (int u = 0; u < 8; ++u) w0[u] = w1[u];
    }
  }
  float4* s4 = reinterpret_cast<float4*>(scr);
#pragma unroll
  for (int r = 0; r < ROWS; ++r)
    s4[(seg * ROWS + r) * OUTG + c] =
        make_float4(acc[r][0], acc[r][1], acc[r][2], acc[r][3]);
  __syncthreads();
  for (int idx = tid; idx < OUT * ROWS; idx += 512) {
    const int r = idx / OUT, j = idx % OUT;
    float v = (bias ? bias[j] : 0.f);
#pragma unroll
    for (int s = 0; s < NSEG; ++s) v += scr[(s * ROWS + r) * OUT + j];
    if (relu) v = fmaxf(v, 0.f);
    out[r * ops + j] = v;
  }
  __syncthreads();
}

// =========================================================================
// denseW (256-thread, 2 col-groups) — kept for kD.
// =========================================================================
template<int K, int OUT, int ROWS>
DEV void denseW(const float* __restrict__ W, const float* __restrict__ bias,
                const float* in, int ips, float* out, int ops, int relu,
                float* scr)
{
  constexpr int OUTG = OUT / 4;
  constexpr int HALF = OUTG / 2;
  constexpr int TPS  = HALF;
  constexpr int NSEG = 256 / TPS;
  constexpr int KS   = K / NSEG;
  constexpr int NG   = KS / 8;
  static_assert(KS % 8 == 0 && NG >= 1, "bad shape");
  const int tid = (int)threadIdx.x;
  const int c   = tid & (TPS - 1);
  const int seg = tid / TPS;
  const int k0  = seg * KS;
  const float4* W4 = reinterpret_cast<const float4*>(W);
  float4 a0[8], b0[8], a1[8], b1[8];
  float acc[ROWS][8];
#pragma unroll
  for (int r = 0; r < ROWS; ++r)
#pragma unroll
    for (int x = 0; x < 8; ++x) acc[r][x] = 0.f;
#pragma unroll
  for (int u = 0; u < 8; ++u) {
    a0[u] = W4[(size_t)(k0 + u) * OUTG + c];
    b0[u] = W4[(size_t)(k0 + u) * OUTG + c + HALF];
  }
#pragma unroll
  for (int t = 1; t <= NG; ++t) {
    if (t < NG) {
#pragma unroll
      for (int u = 0; u < 8; ++u) {
        a1[u] = W4[(size_t)(k0 + t * 8 + u) * OUTG + c];
        b1[u] = W4[(size_t)(k0 + t * 8 + u) * OUTG + c + HALF];
      }
    }
#pragma unroll
    for (int u = 0; u < 8; ++u) {
      const int kk = k0 + (t - 1) * 8 + u;
#pragma unroll
      for (int r = 0; r < ROWS; ++r) {
        const float x = in[r * ips + kk];
        acc[r][0] = fmaf(x, a0[u].x, acc[r][0]);
        acc[r][1] = fmaf(x, a0[u].y, acc[r][1]);
        acc[r][2] = fmaf(x, a0[u].z, acc[r][2]);
        acc[r][3] = fmaf(x, a0[u].w, acc[r][3]);
        acc[r][4] = fmaf(x, b0[u].x, acc[r][4]);
        acc[r][5] = fmaf(x, b0[u].y, acc[r][5]);
        acc[r][6] = fmaf(x, b0[u].z, acc[r][6]);
        acc[r][7] = fmaf(x, b0[u].w, acc[r][7]);
      }
    }
    if (t < NG) {
#pragma unroll
      for (int u = 0; u < 8; ++u) { a0[u] = a1[u]; b0[u] = b1[u]; }
    }
  }
  float4* s4 = reinterpret_cast<float4*>(scr);
#pragma unroll
  for (int r = 0; r < ROWS; ++r) {
    s4[(seg * ROWS + r) * OUTG + c] =
        make_float4(acc[r][0], acc[r][1], acc[r][2], acc[r][3]);
    s4[(seg * ROWS + r) * OUTG + c + HALF] =
        make_float4(acc[r][4], acc[r][5], acc[r][6], acc[r][7]);
  }
  __syncthreads();
  for (int idx = tid; idx < OUT * ROWS; idx += 256) {
    const int r = idx / OUT, j = idx % OUT;
    float v = (bias ? bias[j] : 0.f);
#pragma unroll
    for (int s = 0; s < NSEG; ++s) v += scr[(s * ROWS + r) * OUT + j];
    if (relu) v = fmaxf(v, 0.f);
    out[r * ops + j] = v;
  }
  __syncthreads();
}

// ================= K1a: action MLP first two layers =================
__global__ __launch_bounds__(128) void k_pi_h2(
    const float* __restrict__ actions,
    const float* __restrict__ w1, const float* __restrict__ b1,
    const float* __restrict__ w2, const float* __restrict__ b2,
    float* __restrict__ h2out)
{
  const int row = blockIdx.x;
  const int j = threadIdx.x;
  __shared__ float a[32];
  __shared__ float h1[128];
  if (j < 32) a[j] = actions[row * 32 + j];
  __syncthreads();
  float acc = b1[j];
#pragma unroll
  for (int i = 0; i < 32; ++i) acc = fmaf(a[i], w1[i * 128 + j], acc);
  h1[j] = fmaxf(acc, 0.f);
  __syncthreads();
  float acc2 = b2[j];
#pragma unroll 8
  for (int i = 0; i < 128; ++i) acc2 = fmaf(h1[i], w2[i * 128 + j], acc2);
  h2out[row * 128 + j] = fmaxf(acc2, 0.f);
}

// ================= K1b: h2 @ W3, XCD-aligned: batch = blockIdx.x & 7 =======
// 1D grid of 512: round-robin dispatch puts all 64 blocks of batch y on the
// same XCD as k_rnn's block y -> k_rnn reads hit that XCD's L2 (2MB/batch).
__global__ __launch_bounds__(256) void k_pi_trans(
    const float* __restrict__ h2,
    const float* __restrict__ w3, const float* __restrict__ b3,
    float* __restrict__ trans)
{
  const int batch = blockIdx.x & 7;
  const int colblk = blockIdx.x >> 3;
  const int col = colblk * 256 + threadIdx.x;
  const int r0 = batch * 32;
  __shared__ float h2s[32][128];
  for (int idx = threadIdx.x; idx < 32 * 128; idx += 256)
    h2s[idx >> 7][idx & 127] = h2[(size_t)(r0 + (idx >> 7)) * 128 + (idx & 127)];
  __syncthreads();
  float acc[32];
#pragma unroll
  for (int r = 0; r < 32; ++r) acc[r] = 0.f;
  float w0[8], w1[8];
#pragma unroll
  for (int c = 0; c < 8; ++c) w0[c] = w3[(size_t)c * 16384 + col];
#pragma unroll
  for (int i = 8; i <= 128; i += 8) {
    if (i < 128) {
#pragma unroll
      for (int c = 0; c < 8; ++c) w1[c] = w3[(size_t)(i + c) * 16384 + col];
    }
#pragma unroll
    for (int r = 0; r < 32; ++r) {
      float s = acc[r];
#pragma unroll
      for (int c = 0; c < 8; ++c) s = fmaf(h2s[r][i - 8 + c], w0[c], s);
      acc[r] = s;
    }
    if (i < 128) {
#pragma unroll
      for (int c = 0; c < 8; ++c) w0[c] = w1[c];
    }
  }
  const float bv = b3[col];
#pragma unroll
  for (int r = 0; r < 32; ++r)
    trans[(size_t)(r0 + r) * 16384 + col] = acc[r] + bv;
}

// ================= K2: RNN scan, 1024 threads, 2 barriers/step =============
__global__ __launch_bounds__(1024) void k_rnn(
    const float* __restrict__ trans, const float* __restrict__ rinit,
    float* __restrict__ structural)
{
  const int b = blockIdx.x;
  const int tid = threadIdx.x;
  const int j = tid & 127, seg = tid >> 7;   // 8 segments x 16 rows
  __shared__ float h[128];
  __shared__ float part[8][128];
  if (tid < 64) {
    const float x0 = rinit[tid], x1 = rinit[tid + 64];
    float ss = x0 * x0 + x1 * x1;
#pragma unroll
    for (int s = 32; s > 0; s >>= 1) ss += __shfl_xor(ss, s);
    const float iv = 1.f / fmaxf(sqrtf(ss), 1e-12f);
    h[tid] = x0 * iv;
    h[tid + 64] = x1 * iv;
  }
  __syncthreads();

  float cur[16], nxt[16];
  {
    const float* T0 = trans + ((size_t)(b * 32) << 14);
#pragma unroll
    for (int k = 0; k < 16; ++k) cur[k] = T0[(size_t)(seg * 16 + k) * 128 + j];
  }
  for (int t = 0; t < 32; ++t) {
    if (t < 31) {
      const float* Tn = trans + ((size_t)(b * 32 + t + 1) << 14);
#pragma unroll
      for (int k = 0; k < 16; ++k) nxt[k] = Tn[(size_t)(seg * 16 + k) * 128 + j];
    }
    float acc = 0.f;
#pragma unroll
    for (int k = 0; k < 16; ++k) acc = fmaf(h[seg * 16 + k], cur[k], acc);
    part[seg][j] = acc;
    __syncthreads();
    if (tid < 64) {
      const int l = tid;
      float r0 = part[0][l], r1 = part[0][l + 64];
#pragma unroll
      for (int s = 1; s < 8; ++s) { r0 += part[s][l]; r1 += part[s][l + 64]; }
      r0 = fmaxf(r0, 0.f);
      r1 = fmaxf(r1, 0.f);
      float ss = r0 * r0 + r1 * r1;
#pragma unroll
      for (int s = 32; s > 0; s >>= 1) ss += __shfl_xor(ss, s);
      const float iv = 1.f / fmaxf(sqrtf(ss), 1e-12f);
      const float v0 = r0 * iv, v1 = r1 * iv;
      h[l] = v0;
      h[l + 64] = v1;
      structural[(size_t)(b * 32 + t) * 128 + l] = v0;
      structural[(size_t)(b * 32 + t) * 128 + l + 64] = v1;
    }
    __syncthreads();
    if (t < 31) {
#pragma unroll
      for (int k = 0; k < 16; ++k) cur[k] = nxt[k];
    }
  }
}

// ================= kA: enc + retrieve1+2 + gen/rel losses (512 thr) =========
__global__ __launch_bounds__(512) void kA(
    const float* __restrict__ sensory, const float* __restrict__ structural_,
    const float* __restrict__ enc_w, const float* __restrict__ wq,
    const float* __restrict__ dec_w,
    const float* __restrict__ mw1, const float* __restrict__ mb1,
    const float* __restrict__ mw2, const float* __restrict__ mb2,
    const float* __restrict__ mw3, const float* __restrict__ mb3,
    const float* __restrict__ ow1, const float* __restrict__ ob1,
    const float* __restrict__ ow2, const float* __restrict__ ob2,
    const float* __restrict__ ow3, const float* __restrict__ ob3,
    float* __restrict__ ws_enc, float* __restrict__ ws_dgs,
    float* __restrict__ lossPart)
{
  const int g = blockIdx.x, tid = threadIdx.x;
  __shared__ float sens[512], sRow[128], eRow[128];
  __shared__ float actA[2 * OPS], actB[2 * OPS];
  __shared__ float4 scr4buf[1024];    // 16 KB combine scratch
  __shared__ float red[8];
  float* scr = reinterpret_cast<float*>(scr4buf);

  sens[tid] = sensory[(size_t)g * 512 + tid];
  if (tid < 128) sRow[tid] = structural_[(size_t)g * 128 + tid];
  __syncthreads();

  // enc = sens @ enc_w
  dense512<512, 128, 1>(enc_w, nullptr, sens, 0, eRow, 0, 0, scr);
  if (tid < 128) ws_enc[(size_t)g * 128 + tid] = eRow[tid];

  // q1 = sRow@wq_top, q2 = eRow@wq_bot
  dense512<128, 128, 1>(wq, nullptr, sRow, 0, actA, 0, 0, scr);
  dense512<128, 128, 1>(wq + 128 * 128, nullptr, eRow, 0, actA + OPS, 0, 0, scr);
  dense512<128, 256, 2>(mw1, mb1, actA, OPS, actB, OPS, 1, scr);
  dense512<256, 256, 2>(mw2, mb2, actB, OPS, actA, OPS, 1, scr);
  dense512<256, 128, 2>(mw3, mb3, actA, OPS, actB, OPS, 0, scr);
  dense512<128, 256, 2>(ow1, ob1, actB, OPS, actA, OPS, 1, scr);
  dense512<256, 256, 2>(ow2, ob2, actA, OPS, actB, OPS, 1, scr);
  dense512<256, 256, 2>(ow3, ob3, actB, OPS, actA, OPS, 0, scr);
  // actA row0 = [dgs|dec_enc], row1 = [dec_s2|*]
  float lrel = 0.f;
  if (tid < 128) {
    ws_dgs[(size_t)g * 128 + tid] = actA[tid];
    const float d = actA[OPS + tid] - sRow[tid];
    lrel = d * d;
  }
  const float relT = wgsum512(lrel, red);
  if (tid == 0) lossPart[256 + g] = relT;
  // gen loss
  dense512<128, 512, 1>(dec_w, nullptr, &actA[128], 0, actB, 0, 0, scr);
  {
    const float d = actB[tid] - sens[tid];
    const float genT = wgsum512(d * d, red);
    if (tid == 0) lossPart[g] = genT;
  }
}

// ================= kBC: retrieve3 + pred_var + retrieve4 + keys/vals/hp =====
__global__ __launch_bounds__(512) void kBC(
    const float* __restrict__ sensory,
    const float* __restrict__ ws_enc, const float* __restrict__ ws_dgs,
    const float* __restrict__ wq, const float* __restrict__ dec_w,
    const float* __restrict__ mw1, const float* __restrict__ mb1,
    const float* __restrict__ mw2, const float* __restrict__ mb2,
    const float* __restrict__ mw3, const float* __restrict__ mb3,
    const float* __restrict__ ow1, const float* __restrict__ ob1,
    const float* __restrict__ ow2, const float* __restrict__ ob2,
    const float* __restrict__ ow3, const float* __restrict__ ob3,
    const float* __restrict__ vw1, const float* __restrict__ vb1,
    const float* __restrict__ vw2, const float* __restrict__ vb2,
    const float* __restrict__ vw3, const float* __restrict__ vb3,
    const float* __restrict__ wk, const float* __restrict__ wv,
    const float* __restrict__ w_hp, const float* __restrict__ ir,
    float* __restrict__ gKeys, float* __restrict__ gVals,
    float* __restrict__ gHp, float* __restrict__ lossPart)
{
  const int g = blockIdx.x, tid = threadIdx.x;
  __shared__ float sens[512], eRow[128], dgsRow[128], cRow[128], infRow[128];
  __shared__ float cbuf[256];
  __shared__ float actA[2 * OPS], actB[2 * OPS];
  __shared__ float4 scr4buf[1024];
  __shared__ float red[8];
  float* scr = reinterpret_cast<float*>(scr4buf);

  sens[tid] = sensory[(size_t)g * 512 + tid];
  if (tid < 128) eRow[tid] = ws_enc[(size_t)g * 128 + tid];
  else if (tid < 256) dgsRow[tid - 128] = ws_dgs[(size_t)g * 128 + (tid - 128)];
  __syncthreads();

  // ---- retrieve 3 ----
  if (tid < 256) cbuf[tid] = (tid < 128) ? dgsRow[tid] : eRow[tid - 128];
  __syncthreads();
  dense512<256, 128, 1>(wq, nullptr, cbuf, 0, actA, 0, 0, scr);    // q3
  dense512<128, 256, 1>(mw1, mb1, actA, 0, actB, 0, 1, scr);
  dense512<256, 256, 1>(mw2, mb2, actB, 0, actA, 0, 1, scr);
  dense512<256, 128, 1>(mw3, mb3, actA, 0, actB, 0, 0, scr);
  dense512<128, 256, 1>(ow1, ob1, actB, 0, actA, 0, 1, scr);
  dense512<256, 256, 1>(ow2, ob2, actA, 0, actB, 0, 1, scr);
  dense512<256, 256, 1>(ow3, ob3, actB, 0, actA, 0, 0, scr);       // [corr|corr_e]
  float ls = 0.f;
  if (tid < 128) {
    cRow[tid] = actA[tid];
    const float d = actA[128 + tid] - eRow[tid];
    ls = d * d;
  }
  const float sseV = wgsum512(ls, red);

  // ---- pred_var -> inf_s (LDS only) ----
  if (tid < 256) cbuf[tid] = (tid < 128) ? cRow[tid] : dgsRow[tid - 128];
  __syncthreads();
  dense512<256, 256, 1>(vw1, vb1, cbuf, 0, actB, 0, 0, scr);
  if (tid < 256)
    actB[tid] = fmaxf(actB[tid] + sseV * vw1[(size_t)256 * 256 + tid], 0.f);
  __syncthreads();
  dense512<256, 256, 1>(vw2, vb2, actB, 0, actA, 0, 1, scr);
  dense512<256, 128, 1>(vw3, vb3, actA, 0, actB, 0, 0, scr);       // pv
  const float sig = sigm(ir[0]);
  float lc = 0.f;
  if (tid < 128) {
    const float diff = (cRow[tid] - dgsRow[tid]) * sig * actB[tid];
    infRow[tid] = dgsRow[tid] + diff;
    lc = diff * diff;
  }
  const float consT = wgsum512(lc, red);
  if (tid == 0) lossPart[512 + g] = consT;
  __syncthreads();

  // ---- retrieve 4 ----
  dense512<128, 128, 1>(wq, nullptr, infRow, 0, actA, 0, 0, scr);  // q4
  dense512<128, 256, 1>(mw1, mb1, actA, 0, actB, 0, 1, scr);
  dense512<256, 256, 1>(mw2, mb2, actB, 0, actA, 0, 1, scr);
  dense512<256, 128, 1>(mw3, mb3, actA, 0, actB, 0, 0, scr);
  dense512<128, 256, 1>(ow1, ob1, actB, 0, actA, 0, 1, scr);
  dense512<256, 256, 1>(ow2, ob2, actA, 0, actB, 0, 1, scr);
  dense512<256, 256, 1>(ow3, ob3, actB, 0, actA, 0, 0, scr);       // [finalS|inf_e]
  dense512<128, 512, 1>(dec_w, nullptr, &actA[128], 0, actB, 0, 0, scr);
  {
    const float d = actB[tid] - sens[tid];
    const float infT = wgsum512(d * d, red);
    if (tid == 0) lossPart[768 + g] = infT;
  }
  __syncthreads();

  // ---- keys / vals / hp ----
  if (tid < 256) cbuf[tid] = (tid < 128) ? actA[tid] : eRow[tid - 128];
  __syncthreads();
  dense512<256, 128, 1>(wk, nullptr, cbuf, 0, gKeys + (size_t)g * 128, 0, 0, scr);
  dense512<256, 128, 1>(wv, nullptr, cbuf, 0, gVals + (size_t)g * 128, 0, 0, scr);
  const int c = tid >> 6, l = tid & 63;
  float acc = 0.f;
  if (c < 3) {
    for (int i = l; i < 256; i += 64)
      acc = fmaf(cbuf[i], w_hp[i * 3 + c], acc);
  }
#pragma unroll
  for (int s = 32; s > 0; s >>= 1) acc += __shfl_xor(acc, s);
  if (c < 3 && l == 0) gHp[(size_t)g * 4 + c] = acc;
}

// ================= kD: meta fwd/bwd (blocks 0-255) + coef scan (block 256) =================
__global__ __launch_bounds__(256) void kD(
    const float* __restrict__ gKeys, const float* __restrict__ gVals,
    const float* __restrict__ gHp,
    const float* __restrict__ mw1, const float* __restrict__ mb1,
    const float* __restrict__ mw2, const float* __restrict__ mb2,
    const float* __restrict__ mw3, const float* __restrict__ mb3,
    float* __restrict__ ws_h1, float* __restrict__ ws_h2,
    float* __restrict__ ws_d1, float* __restrict__ ws_d2, float* __restrict__ ws_d3,
    float* __restrict__ wA, float* __restrict__ wU, float* __restrict__ Ft)
{
  const int tid = threadIdx.x;
  __shared__ float kRow[128], vRow[128];
  __shared__ float actA[256], actB[256], d3R[128], d2R[256];
  __shared__ float4 scr4buf[1024];
  __shared__ float lr[256], sf[256], sb[256];
  float* scr = reinterpret_cast<float*>(scr4buf);
  if (blockIdx.x == 256) {
    lr[tid] = gHp[(size_t)tid * 4 + 0];
    sf[tid] = sigm(gHp[(size_t)tid * 4 + 1]);
    sb[tid] = sigm(gHp[(size_t)tid * 4 + 2]);
    __syncthreads();
    if (tid < 8) {
      const int b = tid;
      float cB = 1.f, cF = 1.f, Bv = 1.f;
      wU[b * 32 + 31] = lr[b * 32 + 31];
      wA[b * 32 + 31] = lr[b * 32 + 31];
      for (int t = 30; t >= 0; --t) {
        cB = sb[b * 32 + t + 1] * cB;
        cF = sf[b * 32 + t + 1] * cF;
        Bv = cF + sb[b * 32 + t + 1] * Bv;
        wU[b * 32 + t] = lr[b * 32 + t] * cB;
        wA[b * 32 + t] = lr[b * 32 + t] * Bv;
      }
      float ft = 1.f;
      for (int t = 0; t < 32; ++t) ft *= sf[b * 32 + t];
      Ft[b] = ft;
    }
    return;
  }
  const int g = blockIdx.x;
  if (tid < 128) kRow[tid] = gKeys[(size_t)g * 128 + tid];
  else vRow[tid - 128] = gVals[(size_t)g * 128 + (tid - 128)];
  __syncthreads();
  denseW<128, 256, 1>(mw1, mb1, kRow, 0, actA, 0, 1, scr);
  ws_h1[(size_t)g * 256 + tid] = actA[tid];
  denseW<256, 256, 1>(mw2, mb2, actA, 0, actB, 0, 1, scr);
  ws_h2[(size_t)g * 256 + tid] = actB[tid];
  denseW<256, 128, 1>(mw3, mb3, actB, 0, d3R, 0, 0, scr);
  if (tid < 128) {
    const float d = (d3R[tid] - vRow[tid]) * (2.f / 128.f);
    d3R[tid] = d;
    ws_d3[(size_t)g * 128 + tid] = d;
  }
  __syncthreads();
  // d2 = relu'(h2) * (mw3 row j . d3)
  {
    const int j = tid;
    float acc = 0.f;
    for (int jc = 0; jc < 128; jc += 4) {
      const float4 w = *reinterpret_cast<const float4*>(&mw3[(size_t)j * 128 + jc]);
      acc = fmaf(w.x, d3R[jc + 0], acc);
      acc = fmaf(w.y, d3R[jc + 1], acc);
      acc = fmaf(w.z, d3R[jc + 2], acc);
      acc = fmaf(w.w, d3R[jc + 3], acc);
    }
    const float v = (actB[j] > 0.f) ? acc : 0.f;
    d2R[j] = v;
    ws_d2[(size_t)g * 256 + j] = v;
  }
  __syncthreads();
  // d1 = relu'(h1) * (mw2 row j . d2)
  {
    const int j = tid;
    float acc = 0.f;
    for (int jc = 0; jc < 256; jc += 4) {
      const float4 w = *reinterpret_cast<const float4*>(&mw2[(size_t)j * 256 + jc]);
      acc = fmaf(w.x, d2R[jc + 0], acc);
      acc = fmaf(w.y, d2R[jc + 1], acc);
      acc = fmaf(w.z, d2R[jc + 2], acc);
      acc = fmaf(w.w, d2R[jc + 3], acc);
    }
    ws_d1[(size_t)g * 256 + j] = (actA[j] > 0.f) ? acc : 0.f;
  }
}

// ================= kW: outer products + bias + final =================
DEV void outer_body(const float* __restrict__ L, int Lld,
                    const float* __restrict__ D, int Dld,
                    const float* __restrict__ P,
                    const float* __restrict__ wA, const float* __restrict__ wU,
                    const float* __restrict__ Ftot,
                    float* __restrict__ out, size_t regionOff, int J,
                    int b, int i0, float* __restrict__ wAk, float* __restrict__ wUk)
{
  const int tid = threadIdx.x;
  for (int idx = tid; idx < 1024; idx += 256) {
    const int t = idx >> 5, ii = idx & 31;
    const float kv = L[(size_t)(b * 32 + t) * Lld + i0 + ii];
    wAk[t * 33 + ii] = wA[b * 32 + t] * kv;
    wUk[t * 33 + ii] = wU[b * 32 + t] * kv;
  }
  __syncthreads();
  const int j = (J == 256) ? tid : (tid & 127);
  const int g2 = (J == 256) ? 0 : (tid >> 7);
  const int span = (J == 256) ? 32 : 16;
  const int iBeg = g2 * span;
  float dv[32];
#pragma unroll
  for (int t = 0; t < 32; ++t) dv[t] = D[(size_t)(b * 32 + t) * Dld + j];
  const float ft = Ftot[b];
  float* ob = out + 1 + (size_t)b * (2 * W_TOT);
  for (int ii = iBeg; ii < iBeg + span; ++ii) {
    float aA = 0.f, aU = 0.f;
#pragma unroll
    for (int t = 0; t < 32; ++t) {
      aA = fmaf(wAk[t * 33 + ii], dv[t], aA);
      aU = fmaf(wUk[t * 33 + ii], dv[t], aU);
    }
    const int i = i0 + ii;
    const size_t w = regionOff + (size_t)i * J + j;
    ob[w] = ft * P[(size_t)i * J + j] - aA;
    ob[W_TOT + w] = aU;
  }
}

__global__ __launch_bounds__(256) void kW(
    const float* __restrict__ keys, const float* __restrict__ h1,
    const float* __restrict__ h2, const float* __restrict__ d1,
    const float* __restrict__ d2, const float* __restrict__ d3,
    const float* __restrict__ mw1, const float* __restrict__ mb1,
    const float* __restrict__ mw2, const float* __restrict__ mb2,
    const float* __restrict__ mw3, const float* __restrict__ mb3,
    const float* __restrict__ wA, const float* __restrict__ wU,
    const float* __restrict__ Ft, const float* __restrict__ lossPart,
    float* __restrict__ out)
{
  __shared__ float wAk[32 * 33], wUk[32 * 33];
  __shared__ float red[4];
  const int bid = blockIdx.x;
  const int tid = threadIdx.x;
  if (bid < 32) {
    outer_body(keys, 128, d1, 256, mw1, wA, wU, Ft, out, OFF_W1, 256,
               bid >> 2, (bid & 3) * 32, wAk, wUk);
  } else if (bid < 96) {
    const int x = bid - 32;
    outer_body(h1, 256, d2, 256, mw2, wA, wU, Ft, out, OFF_W2, 256,
               x >> 3, (x & 7) * 32, wAk, wUk);
  } else if (bid < 160) {
    const int x = bid - 96;
    outer_body(h2, 256, d3, 128, mw3, wA, wU, Ft, out, OFF_W3, 128,
               x >> 3, (x & 7) * 32, wAk, wUk);
  } else if (bid < 168) {
    const int b = bid - 160;
    const float ft = Ft[b];
    float* ob = out + 1 + (size_t)b * (2 * W_TOT);
    for (int idx = tid; idx < 640; idx += 256) {
      const float* D; int ld, j; size_t off; float pv;
      if (idx < 256)      { D = d1; ld = 256; j = idx;       off = OFF_B1; pv = mb1[j]; }
      else if (idx < 512) { D = d2; ld = 256; j = idx - 256; off = OFF_B2; pv = mb2[j]; }
      else                { D = d3; ld = 128; j = idx - 512; off = OFF_B3; pv = mb3[j]; }
      float aA = 0.f, aU = 0.f;
#pragma unroll
      for (int t = 0; t < 32; ++t) {
        const float dv = D[(size_t)(b * 32 + t) * ld + j];
        aA = fmaf(wA[b * 32 + t], dv, aA);
        aU = fmaf(wU[b * 32 + t], dv, aU);
      }
      ob[off + j] = ft * pv - aA;
      ob[W_TOT + off + j] = aU;
    }
  } else {
    const int c = tid >> 6, l = tid & 63;
    float v = lossPart[c * 256 + l] + lossPart[c * 256 + 64 + l] +
              lossPart[c * 256 + 128 + l] + lossPart[c * 256 + 192 + l];
#pragma unroll
    for (int s = 32; s > 0; s >>= 1) v += __shfl_xor(v, s);
    if (l == 0) red[c] = v;
    __syncthreads();
    if (tid == 0) {
      const float i1 = 1.f / (256.f * 512.f);
      const float i2 = 1.f / (256.f * 128.f);
      out[0] = red[0] * i1 + 2.f * red[1] * i2 + red[2] * i2 + red[3] * i1;
    }
  }
}

// ================= launch =================
extern "C" void kernel_launch(void* const* d_in, const int* in_sizes, int n_in,
                              void* d_out, int out_size, void* d_ws, size_t ws_size,
                              hipStream_t stream)
{
  const float* sensory = (const float*)d_in[0];
  const float* actions = (const float*)d_in[1];
  const float* enc_w = (const float*)d_in[2];
  const float* dec_w = (const float*)d_in[3];
  const float* pi_w1 = (const float*)d_in[4];
  const float* pi_b1 = (const float*)d_in[5];
  const float* pi_w2 = (const float*)d_in[6];
  const float* pi_b2 = (const float*)d_in[7];
  const float* pi_w3 = (const float*)d_in[8];
  const float* pi_b3 = (const float*)d_in[9];
  const float* rinit = (const float*)d_in[10];
  const float* wq = (const float*)d_in[11];
  const float* wk = (const float*)d_in[12];
  const float* wv = (const float*)d_in[13];
  const float* w_hp = (const float*)d_in[14];
  const float* mw1 = (const float*)d_in[15]; const float* mb1 = (const float*)d_in[16];
  const float* mw2 = (const float*)d_in[17]; const float* mb2 = (const float*)d_in[18];
  const float* mw3 = (const float*)d_in[19]; const float* mb3 = (const float*)d_in[20];
  const float* ow1 = (const float*)d_in[21]; const float* ob1 = (const float*)d_in[22];
  const float* ow2 = (const float*)d_in[23]; const float* ob2 = (const float*)d_in[24];
  const float* ow3 = (const float*)d_in[25]; const float* ob3 = (const float*)d_in[26];
  const float* vw1 = (const float*)d_in[27]; const float* vb1 = (const float*)d_in[28];
  const float* vw2 = (const float*)d_in[29]; const float* vb2 = (const float*)d_in[30];
  const float* vw3 = (const float*)d_in[31]; const float* vb3 = (const float*)d_in[32];
  const float* ir  = (const float*)d_in[33];

  float* ws  = (float*)d_ws;
  float* out = (float*)d_out;

  float* lossP = ws + P_LOSS;
  float* wA = ws + P_WA; float* wU = ws + P_WU; float* Ft = ws + P_FT;
  float* hp = ws + P_HP;
  float* h2pi = ws + P_H2PI;
  float* enc = ws + P_ENC;
  float* dgs = ws + P_DGS;
  float* keys = ws + P_KEYS;
  float* vals = ws + P_VALS;
  float* d3s = ws + P_D3;
  float* h1s = ws + P_H1;
  float* h2s = ws + P_H2;
  float* d1s = ws + P_D1;
  float* d2s = ws + P_D2;
  float* structural = ws + P_STRUCT;
  float* trans = ws + P_TRANS;

  hipLaunchKernelGGL(k_pi_h2, dim3(256), dim3(128), 0, stream,
                     actions, pi_w1, pi_b1, pi_w2, pi_b2, h2pi);
  hipLaunchKernelGGL(k_pi_trans, dim3(512), dim3(256), 0, stream,
                     h2pi, pi_w3, pi_b3, trans);
  hipLaunchKernelGGL(k_rnn, dim3(8), dim3(1024), 0, stream, trans, rinit, structural);
  hipLaunchKernelGGL(kA, dim3(256), dim3(512), 0, stream,
                     sensory, structural, enc_w, wq, dec_w,
                     mw1, mb1, mw2, mb2, mw3, mb3,
                     ow1, ob1, ow2, ob2, ow3, ob3,
                     enc, dgs, lossP);
  hipLaunchKernelGGL(kBC, dim3(256), dim3(512), 0, stream,
                     sensory, enc, dgs, wq, dec_w,
                     mw1, mb1, mw2, mb2, mw3, mb3,
                     ow1, ob1, ow2, ob2, ow3, ob3,
                     vw1, vb1, vw2, vb2, vw3, vb3,
                     wk, wv, w_hp, ir, keys, vals, hp, lossP);
  hipLaunchKernelGGL(kD, dim3(257), dim3(256), 0, stream,
                     keys, vals, hp, mw1, mb1, mw2, mb2, mw3, mb3,
                     h1s, h2s, d1s, d2s, d3s, wA, wU, Ft);
  hipLaunchKernelGGL(kW, dim3(169), dim3(256), 0, stream,
                     keys, h1s, h2s, d1s, d2s, d3s,
                     mw1, mb1, mw2, mb2, mw3, mb3,
                     wA, wU, Ft, lossP, out);
}

// Round 17
// 183.428 us; speedup vs baseline: 1.1995x; 1.1995x over previous
//
#include <hip/hip_runtime.h>
#include <cstdint>
#include <cstddef>

#define DEV __device__ __forceinline__

// ---------------- problem constants ----------------
constexpr size_t W_TOT = 131712;
constexpr size_t OFF_W1 = 0;       // [128][256]
constexpr size_t OFF_B1 = 32768;   // [256]
constexpr size_t OFF_W2 = 33024;   // [256][256]
constexpr size_t OFF_B2 = 98560;   // [256]
constexpr size_t OFF_W3 = 98816;   // [256][128]
constexpr size_t OFF_B3 = 131584;  // [128]

constexpr int OPS = 272;           // LDS activation row stride

// ---------------- workspace layout (floats) ----------------
constexpr size_t P_LOSS = 0;                    // [4][256]
constexpr size_t P_WA   = 1024;                 // [8][32]
constexpr size_t P_WU   = 1280;                 // [8][32]
constexpr size_t P_FT   = 1536;                 // [8]
constexpr size_t P_HP   = 2048;                 // [256][4]
constexpr size_t P_H2PI = 4096;                 // [256][128]
constexpr size_t P_ENC  = P_H2PI + 32768;       // [256][128]
constexpr size_t P_DGS  = P_ENC + 32768;        // [256][128]
constexpr size_t P_INF  = P_DGS + 32768;        // [256][128]
constexpr size_t P_KEYS = P_INF + 32768;        // [256][128]
constexpr size_t P_VALS = P_KEYS + 32768;       // [256][128]
constexpr size_t P_D3   = P_VALS + 32768;       // [256][128]
constexpr size_t P_H1   = P_D3 + 32768;         // [256][256]
constexpr size_t P_H2   = P_H1 + 65536;         // [256][256]
constexpr size_t P_D1   = P_H2 + 65536;         // [256][256]
constexpr size_t P_D2   = P_D1 + 65536;         // [256][256]
constexpr size_t P_STRUCT = P_D2 + 65536;       // [256][128]
constexpr size_t P_TRANS  = P_STRUCT + 32768;   // [256][16384]

DEV float sigm(float x) { return 1.f / (1.f + expf(-x)); }

// 512-thread WG sum; returns total to ALL threads.
DEV float wgsum512(float v, float* red) {
#pragma unroll
  for (int s = 32; s > 0; s >>= 1) v += __shfl_xor(v, s);
  if ((threadIdx.x & 63) == 0) red[threadIdx.x >> 6] = v;
  __syncthreads();
  float t = 0.f;
#pragma unroll
  for (int w = 0; w < 8; ++w) t += red[w];
  __syncthreads();
  return t;
}

// =========================================================================
// dense512: 512 threads, one float4 col-group/thread, 8-deep ping-pong,
// cross-thread split-K, LDS combine.
// =========================================================================
template<int K, int OUT, int ROWS>
DEV void dense512(const float* __restrict__ W, const float* __restrict__ bias,
                  const float* in, int ips, float* out, int ops, int relu,
                  float* scr)
{
  constexpr int OUTG = OUT / 4;            // float4 col-groups
  constexpr int NSEG = 512 / OUTG;         // cross-thread K segments
  constexpr int KS   = K / NSEG;           // K elems per segment
  constexpr int NG   = KS / 8;             // 8-deep windows (>=1)
  static_assert(K % NSEG == 0 && KS % 8 == 0 && NG >= 1, "bad shape");
  const int tid = (int)threadIdx.x;
  const int c   = tid & (OUTG - 1);
  const int seg = tid / OUTG;
  const int k0  = seg * KS;
  const float4* W4 = reinterpret_cast<const float4*>(W);
  float4 w0[8], w1[8];
  float acc[ROWS][4];
#pragma unroll
  for (int r = 0; r < ROWS; ++r) {
    acc[r][0] = 0.f; acc[r][1] = 0.f; acc[r][2] = 0.f; acc[r][3] = 0.f;
  }
#pragma unroll
  for (int u = 0; u < 8; ++u) w0[u] = W4[(size_t)(k0 + u) * OUTG + c];
#pragma unroll
  for (int t = 1; t <= NG; ++t) {
    if (t < NG) {
#pragma unroll
      for (int u = 0; u < 8; ++u) w1[u] = W4[(size_t)(k0 + t * 8 + u) * OUTG + c];
    }
#pragma unroll
    for (int u = 0; u < 8; ++u) {
      const int kk = k0 + (t - 1) * 8 + u;
#pragma unroll
      for (int r = 0; r < ROWS; ++r) {
        const float x = in[r * ips + kk];
        acc[r][0] = fmaf(x, w0[u].x, acc[r][0]);
        acc[r][1] = fmaf(x, w0[u].y, acc[r][1]);
        acc[r][2] = fmaf(x, w0[u].z, acc[r][2]);
        acc[r][3] = fmaf(x, w0[u].w, acc[r][3]);
      }
    }
    if (t < NG) {
#pragma unroll
      for (int u = 0; u < 8; ++u) w0[u] = w1[u];
    }
  }
  float4* s4 = reinterpret_cast<float4*>(scr);
#pragma unroll
  for (int r = 0; r < ROWS; ++r)
    s4[(seg * ROWS + r) * OUTG + c] =
        make_float4(acc[r][0], acc[r][1], acc[r][2], acc[r][3]);
  __syncthreads();
  for (int idx = tid; idx < OUT * ROWS; idx += 512) {
    const int r = idx / OUT, j = idx % OUT;
    float v = (bias ? bias[j] : 0.f);
#pragma unroll
    for (int s = 0; s < NSEG; ++s) v += scr[(s * ROWS + r) * OUT + j];
    if (relu) v = fmaxf(v, 0.f);
    out[r * ops + j] = v;
  }
  __syncthreads();
}

// =========================================================================
// denseW (256-thread, 2 col-groups) — kept for kD.
// =========================================================================
template<int K, int OUT, int ROWS>
DEV void denseW(const float* __restrict__ W, const float* __restrict__ bias,
                const float* in, int ips, float* out, int ops, int relu,
                float* scr)
{
  constexpr int OUTG = OUT / 4;
  constexpr int HALF = OUTG / 2;
  constexpr int TPS  = HALF;
  constexpr int NSEG = 256 / TPS;
  constexpr int KS   = K / NSEG;
  constexpr int NG   = KS / 8;
  static_assert(KS % 8 == 0 && NG >= 1, "bad shape");
  const int tid = (int)threadIdx.x;
  const int c   = tid & (TPS - 1);
  const int seg = tid / TPS;
  const int k0  = seg * KS;
  const float4* W4 = reinterpret_cast<const float4*>(W);
  float4 a0[8], b0[8], a1[8], b1[8];
  float acc[ROWS][8];
#pragma unroll
  for (int r = 0; r < ROWS; ++r)
#pragma unroll
    for (int x = 0; x < 8; ++x) acc[r][x] = 0.f;
#pragma unroll
  for (int u = 0; u < 8; ++u) {
    a0[u] = W4[(size_t)(k0 + u) * OUTG + c];
    b0[u] = W4[(size_t)(k0 + u) * OUTG + c + HALF];
  }
#pragma unroll
  for (int t = 1; t <= NG; ++t) {
    if (t < NG) {
#pragma unroll
      for (int u = 0; u < 8; ++u) {
        a1[u] = W4[(size_t)(k0 + t * 8 + u) * OUTG + c];
        b1[u] = W4[(size_t)(k0 + t * 8 + u) * OUTG + c + HALF];
      }
    }
#pragma unroll
    for (int u = 0; u < 8; ++u) {
      const int kk = k0 + (t - 1) * 8 + u;
#pragma unroll
      for (int r = 0; r < ROWS; ++r) {
        const float x = in[r * ips + kk];
        acc[r][0] = fmaf(x, a0[u].x, acc[r][0]);
        acc[r][1] = fmaf(x, a0[u].y, acc[r][1]);
        acc[r][2] = fmaf(x, a0[u].z, acc[r][2]);
        acc[r][3] = fmaf(x, a0[u].w, acc[r][3]);
        acc[r][4] = fmaf(x, b0[u].x, acc[r][4]);
        acc[r][5] = fmaf(x, b0[u].y, acc[r][5]);
        acc[r][6] = fmaf(x, b0[u].z, acc[r][6]);
        acc[r][7] = fmaf(x, b0[u].w, acc[r][7]);
      }
    }
    if (t < NG) {
#pragma unroll
      for (int u = 0; u < 8; ++u) { a0[u] = a1[u]; b0[u] = b1[u]; }
    }
  }
  float4* s4 = reinterpret_cast<float4*>(scr);
#pragma unroll
  for (int r = 0; r < ROWS; ++r) {
    s4[(seg * ROWS + r) * OUTG + c] =
        make_float4(acc[r][0], acc[r][1], acc[r][2], acc[r][3]);
    s4[(seg * ROWS + r) * OUTG + c + HALF] =
        make_float4(acc[r][4], acc[r][5], acc[r][6], acc[r][7]);
  }
  __syncthreads();
  for (int idx = tid; idx < OUT * ROWS; idx += 256) {
    const int r = idx / OUT, j = idx % OUT;
    float v = (bias ? bias[j] : 0.f);
#pragma unroll
    for (int s = 0; s < NSEG; ++s) v += scr[(s * ROWS + r) * OUT + j];
    if (relu) v = fmaxf(v, 0.f);
    out[r * ops + j] = v;
  }
  __syncthreads();
}

// ================= K1a: action MLP first two layers =================
__global__ __launch_bounds__(128) void k_pi_h2(
    const float* __restrict__ actions,
    const float* __restrict__ w1, const float* __restrict__ b1,
    const float* __restrict__ w2, const float* __restrict__ b2,
    float* __restrict__ h2out)
{
  const int row = blockIdx.x;
  const int j = threadIdx.x;
  __shared__ float a[32];
  __shared__ float h1[128];
  if (j < 32) a[j] = actions[row * 32 + j];
  __syncthreads();
  float acc = b1[j];
#pragma unroll
  for (int i = 0; i < 32; ++i) acc = fmaf(a[i], w1[i * 128 + j], acc);
  h1[j] = fmaxf(acc, 0.f);
  __syncthreads();
  float acc2 = b2[j];
#pragma unroll 8
  for (int i = 0; i < 128; ++i) acc2 = fmaf(h1[i], w2[i * 128 + j], acc2);
  h2out[row * 128 + j] = fmaxf(acc2, 0.f);
}

// ================= K1b: h2 @ W3, XCD-aligned: batch = blockIdx.x & 7 =======
__global__ __launch_bounds__(256) void k_pi_trans(
    const float* __restrict__ h2,
    const float* __restrict__ w3, const float* __restrict__ b3,
    float* __restrict__ trans)
{
  const int batch = blockIdx.x & 7;
  const int colblk = blockIdx.x >> 3;
  const int col = colblk * 256 + threadIdx.x;
  const int r0 = batch * 32;
  __shared__ float h2s[32][128];
  for (int idx = threadIdx.x; idx < 32 * 128; idx += 256)
    h2s[idx >> 7][idx & 127] = h2[(size_t)(r0 + (idx >> 7)) * 128 + (idx & 127)];
  __syncthreads();
  float acc[32];
#pragma unroll
  for (int r = 0; r < 32; ++r) acc[r] = 0.f;
  float w0[8], w1[8];
#pragma unroll
  for (int c = 0; c < 8; ++c) w0[c] = w3[(size_t)c * 16384 + col];
#pragma unroll
  for (int i = 8; i <= 128; i += 8) {
    if (i < 128) {
#pragma unroll
      for (int c = 0; c < 8; ++c) w1[c] = w3[(size_t)(i + c) * 16384 + col];
    }
#pragma unroll
    for (int r = 0; r < 32; ++r) {
      float s = acc[r];
#pragma unroll
      for (int c = 0; c < 8; ++c) s = fmaf(h2s[r][i - 8 + c], w0[c], s);
      acc[r] = s;
    }
    if (i < 128) {
#pragma unroll
      for (int c = 0; c < 8; ++c) w0[c] = w1[c];
    }
  }
  const float bv = b3[col];
#pragma unroll
  for (int r = 0; r < 32; ++r)
    trans[(size_t)(r0 + r) * 16384 + col] = acc[r] + bv;
}

// ================= K2: RNN scan, 1024 threads, 2 barriers/step =============
__global__ __launch_bounds__(1024) void k_rnn(
    const float* __restrict__ trans, const float* __restrict__ rinit,
    float* __restrict__ structural)
{
  const int b = blockIdx.x;
  const int tid = threadIdx.x;
  const int j = tid & 127, seg = tid >> 7;   // 8 segments x 16 rows
  __shared__ float h[128];
  __shared__ float part[8][128];
  if (tid < 64) {
    const float x0 = rinit[tid], x1 = rinit[tid + 64];
    float ss = x0 * x0 + x1 * x1;
#pragma unroll
    for (int s = 32; s > 0; s >>= 1) ss += __shfl_xor(ss, s);
    const float iv = 1.f / fmaxf(sqrtf(ss), 1e-12f);
    h[tid] = x0 * iv;
    h[tid + 64] = x1 * iv;
  }
  __syncthreads();

  float cur[16], nxt[16];
  {
    const float* T0 = trans + ((size_t)(b * 32) << 14);
#pragma unroll
    for (int k = 0; k < 16; ++k) cur[k] = T0[(size_t)(seg * 16 + k) * 128 + j];
  }
  for (int t = 0; t < 32; ++t) {
    if (t < 31) {
      const float* Tn = trans + ((size_t)(b * 32 + t + 1) << 14);
#pragma unroll
      for (int k = 0; k < 16; ++k) nxt[k] = Tn[(size_t)(seg * 16 + k) * 128 + j];
    }
    float acc = 0.f;
#pragma unroll
    for (int k = 0; k < 16; ++k) acc = fmaf(h[seg * 16 + k], cur[k], acc);
    part[seg][j] = acc;
    __syncthreads();
    if (tid < 64) {
      const int l = tid;
      float r0 = part[0][l], r1 = part[0][l + 64];
#pragma unroll
      for (int s = 1; s < 8; ++s) { r0 += part[s][l]; r1 += part[s][l + 64]; }
      r0 = fmaxf(r0, 0.f);
      r1 = fmaxf(r1, 0.f);
      float ss = r0 * r0 + r1 * r1;
#pragma unroll
      for (int s = 32; s > 0; s >>= 1) ss += __shfl_xor(ss, s);
      const float iv = 1.f / fmaxf(sqrtf(ss), 1e-12f);
      const float v0 = r0 * iv, v1 = r1 * iv;
      h[l] = v0;
      h[l + 64] = v1;
      structural[(size_t)(b * 32 + t) * 128 + l] = v0;
      structural[(size_t)(b * 32 + t) * 128 + l + 64] = v1;
    }
    __syncthreads();
    if (t < 31) {
#pragma unroll
      for (int k = 0; k < 16; ++k) cur[k] = nxt[k];
    }
  }
}

// ================= kA: enc + retrieve1+2 + gen/rel losses (512 thr) =========
__global__ __launch_bounds__(512) void kA(
    const float* __restrict__ sensory, const float* __restrict__ structural_,
    const float* __restrict__ enc_w, const float* __restrict__ wq,
    const float* __restrict__ dec_w,
    const float* __restrict__ mw1, const float* __restrict__ mb1,
    const float* __restrict__ mw2, const float* __restrict__ mb2,
    const float* __restrict__ mw3, const float* __restrict__ mb3,
    const float* __restrict__ ow1, const float* __restrict__ ob1,
    const float* __restrict__ ow2, const float* __restrict__ ob2,
    const float* __restrict__ ow3, const float* __restrict__ ob3,
    float* __restrict__ ws_enc, float* __restrict__ ws_dgs,
    float* __restrict__ lossPart)
{
  const int g = blockIdx.x, tid = threadIdx.x;
  __shared__ float sens[512], sRow[128], eRow[128];
  __shared__ float actA[2 * OPS], actB[2 * OPS];
  __shared__ float4 scr4buf[1024];    // 16 KB combine scratch
  __shared__ float red[8];
  float* scr = reinterpret_cast<float*>(scr4buf);

  sens[tid] = sensory[(size_t)g * 512 + tid];
  if (tid < 128) sRow[tid] = structural_[(size_t)g * 128 + tid];
  __syncthreads();

  // enc = sens @ enc_w
  dense512<512, 128, 1>(enc_w, nullptr, sens, 0, eRow, 0, 0, scr);
  if (tid < 128) ws_enc[(size_t)g * 128 + tid] = eRow[tid];

  // q1 = sRow@wq_top, q2 = eRow@wq_bot
  dense512<128, 128, 1>(wq, nullptr, sRow, 0, actA, 0, 0, scr);
  dense512<128, 128, 1>(wq + 128 * 128, nullptr, eRow, 0, actA + OPS, 0, 0, scr);
  dense512<128, 256, 2>(mw1, mb1, actA, OPS, actB, OPS, 1, scr);
  dense512<256, 256, 2>(mw2, mb2, actB, OPS, actA, OPS, 1, scr);
  dense512<256, 128, 2>(mw3, mb3, actA, OPS, actB, OPS, 0, scr);
  dense512<128, 256, 2>(ow1, ob1, actB, OPS, actA, OPS, 1, scr);
  dense512<256, 256, 2>(ow2, ob2, actA, OPS, actB, OPS, 1, scr);
  dense512<256, 256, 2>(ow3, ob3, actB, OPS, actA, OPS, 0, scr);
  // actA row0 = [dgs|dec_enc], row1 = [dec_s2|*]
  float lrel = 0.f;
  if (tid < 128) {
    ws_dgs[(size_t)g * 128 + tid] = actA[tid];
    const float d = actA[OPS + tid] - sRow[tid];
    lrel = d * d;
  }
  const float relT = wgsum512(lrel, red);
  if (tid == 0) lossPart[256 + g] = relT;
  // gen loss
  dense512<128, 512, 1>(dec_w, nullptr, &actA[128], 0, actB, 0, 0, scr);
  {
    const float d = actB[tid] - sens[tid];
    const float genT = wgsum512(d * d, red);
    if (tid == 0) lossPart[g] = genT;
  }
}

// ================= kB: retrieve3 + sse + pred_var + inf_s (512 thr) =========
__global__ __launch_bounds__(512) void kB(
    const float* __restrict__ ws_enc, const float* __restrict__ ws_dgs,
    const float* __restrict__ wq,
    const float* __restrict__ mw1, const float* __restrict__ mb1,
    const float* __restrict__ mw2, const float* __restrict__ mb2,
    const float* __restrict__ mw3, const float* __restrict__ mb3,
    const float* __restrict__ ow1, const float* __restrict__ ob1,
    const float* __restrict__ ow2, const float* __restrict__ ob2,
    const float* __restrict__ ow3, const float* __restrict__ ob3,
    const float* __restrict__ vw1, const float* __restrict__ vb1,
    const float* __restrict__ vw2, const float* __restrict__ vb2,
    const float* __restrict__ vw3, const float* __restrict__ vb3,
    const float* __restrict__ ir,
    float* __restrict__ ws_inf, float* __restrict__ lossPart)
{
  const int g = blockIdx.x, tid = threadIdx.x;
  __shared__ float eRow[128], dgsRow[128], cRow[128];
  __shared__ float cbuf[256];
  __shared__ float actA[2 * OPS], actB[2 * OPS];
  __shared__ float4 scr4buf[1024];
  __shared__ float red[8];
  float* scr = reinterpret_cast<float*>(scr4buf);

  if (tid < 128) eRow[tid] = ws_enc[(size_t)g * 128 + tid];
  else if (tid < 256) dgsRow[tid - 128] = ws_dgs[(size_t)g * 128 + (tid - 128)];
  __syncthreads();

  if (tid < 256) cbuf[tid] = (tid < 128) ? dgsRow[tid] : eRow[tid - 128];
  __syncthreads();
  dense512<256, 128, 1>(wq, nullptr, cbuf, 0, actA, 0, 0, scr);    // q3
  dense512<128, 256, 1>(mw1, mb1, actA, 0, actB, 0, 1, scr);
  dense512<256, 256, 1>(mw2, mb2, actB, 0, actA, 0, 1, scr);
  dense512<256, 128, 1>(mw3, mb3, actA, 0, actB, 0, 0, scr);
  dense512<128, 256, 1>(ow1, ob1, actB, 0, actA, 0, 1, scr);
  dense512<256, 256, 1>(ow2, ob2, actA, 0, actB, 0, 1, scr);
  dense512<256, 256, 1>(ow3, ob3, actB, 0, actA, 0, 0, scr);       // [corr|corr_e]
  float ls = 0.f;
  if (tid < 128) {
    cRow[tid] = actA[tid];
    const float d = actA[128 + tid] - eRow[tid];
    ls = d * d;
  }
  const float sseV = wgsum512(ls, red);

  if (tid < 256) cbuf[tid] = (tid < 128) ? cRow[tid] : dgsRow[tid - 128];
  __syncthreads();
  dense512<256, 256, 1>(vw1, vb1, cbuf, 0, actB, 0, 0, scr);
  if (tid < 256)
    actB[tid] = fmaxf(actB[tid] + sseV * vw1[(size_t)256 * 256 + tid], 0.f);
  __syncthreads();
  dense512<256, 256, 1>(vw2, vb2, actB, 0, actA, 0, 1, scr);
  dense512<256, 128, 1>(vw3, vb3, actA, 0, actB, 0, 0, scr);       // pv
  const float sig = sigm(ir[0]);
  float lc = 0.f;
  if (tid < 128) {
    const float diff = (cRow[tid] - dgsRow[tid]) * sig * actB[tid];
    ws_inf[(size_t)g * 128 + tid] = dgsRow[tid] + diff;
    lc = diff * diff;
  }
  const float consT = wgsum512(lc, red);
  if (tid == 0) lossPart[512 + g] = consT;
}

// ================= kC: retrieve4 + inf loss + keys/vals/hp (512 thr) ========
__global__ __launch_bounds__(512) void kC(
    const float* __restrict__ sensory,
    const float* __restrict__ ws_enc, const float* __restrict__ ws_inf,
    const float* __restrict__ wq, const float* __restrict__ dec_w,
    const float* __restrict__ mw1, const float* __restrict__ mb1,
    const float* __restrict__ mw2, const float* __restrict__ mb2,
    const float* __restrict__ mw3, const float* __restrict__ mb3,
    const float* __restrict__ ow1, const float* __restrict__ ob1,
    const float* __restrict__ ow2, const float* __restrict__ ob2,
    const float* __restrict__ ow3, const float* __restrict__ ob3,
    const float* __restrict__ wk, const float* __restrict__ wv,
    const float* __restrict__ w_hp,
    float* __restrict__ gKeys, float* __restrict__ gVals,
    float* __restrict__ gHp, float* __restrict__ lossPart)
{
  const int g = blockIdx.x, tid = threadIdx.x;
  __shared__ float sens[512], eRow[128], infRow[128];
  __shared__ float cbuf[256];
  __shared__ float actA[2 * OPS], actB[2 * OPS];
  __shared__ float4 scr4buf[1024];
  __shared__ float red[8];
  float* scr = reinterpret_cast<float*>(scr4buf);

  sens[tid] = sensory[(size_t)g * 512 + tid];
  if (tid < 128) eRow[tid] = ws_enc[(size_t)g * 128 + tid];
  else if (tid < 256) infRow[tid - 128] = ws_inf[(size_t)g * 128 + (tid - 128)];
  __syncthreads();

  dense512<128, 128, 1>(wq, nullptr, infRow, 0, actA, 0, 0, scr);  // q4
  dense512<128, 256, 1>(mw1, mb1, actA, 0, actB, 0, 1, scr);
  dense512<256, 256, 1>(mw2, mb2, actB, 0, actA, 0, 1, scr);
  dense512<256, 128, 1>(mw3, mb3, actA, 0, actB, 0, 0, scr);
  dense512<128, 256, 1>(ow1, ob1, actB, 0, actA, 0, 1, scr);
  dense512<256, 256, 1>(ow2, ob2, actA, 0, actB, 0, 1, scr);
  dense512<256, 256, 1>(ow3, ob3, actB, 0, actA, 0, 0, scr);       // [finalS|inf_e]
  dense512<128, 512, 1>(dec_w, nullptr, &actA[128], 0, actB, 0, 0, scr);
  {
    const float d = actB[tid] - sens[tid];
    const float infT = wgsum512(d * d, red);
    if (tid == 0) lossPart[768 + g] = infT;
  }
  __syncthreads();

  if (tid < 256) cbuf[tid] = (tid < 128) ? actA[tid] : eRow[tid - 128];
  __syncthreads();
  dense512<256, 128, 1>(wk, nullptr, cbuf, 0, gKeys + (size_t)g * 128, 0, 0, scr);
  dense512<256, 128, 1>(wv, nullptr, cbuf, 0, gVals + (size_t)g * 128, 0, 0, scr);
  const int c = tid >> 6, l = tid & 63;
  float acc = 0.f;
  if (c < 3) {
    for (int i = l; i < 256; i += 64)
      acc = fmaf(cbuf[i], w_hp[i * 3 + c], acc);
  }
#pragma unroll
  for (int s = 32; s > 0; s >>= 1) acc += __shfl_xor(acc, s);
  if (c < 3 && l == 0) gHp[(size_t)g * 4 + c] = acc;
}

// ================= kD: meta fwd/bwd (blocks 0-255) + coef scan (block 256) =================
__global__ __launch_bounds__(256) void kD(
    const float* __restrict__ gKeys, const float* __restrict__ gVals,
    const float* __restrict__ gHp,
    const float* __restrict__ mw1, const float* __restrict__ mb1,
    const float* __restrict__ mw2, const float* __restrict__ mb2,
    const float* __restrict__ mw3, const float* __restrict__ mb3,
    float* __restrict__ ws_h1, float* __restrict__ ws_h2,
    float* __restrict__ ws_d1, float* __restrict__ ws_d2, float* __restrict__ ws_d3,
    float* __restrict__ wA, float* __restrict__ wU, float* __restrict__ Ft)
{
  const int tid = threadIdx.x;
  __shared__ float kRow[128], vRow[128];
  __shared__ float actA[256], actB[256], d3R[128], d2R[256];
  __shared__ float4 scr4buf[1024];
  __shared__ float lr[256], sf[256], sb[256];
  float* scr = reinterpret_cast<float*>(scr4buf);
  if (blockIdx.x == 256) {
    lr[tid] = gHp[(size_t)tid * 4 + 0];
    sf[tid] = sigm(gHp[(size_t)tid * 4 + 1]);
    sb[tid] = sigm(gHp[(size_t)tid * 4 + 2]);
    __syncthreads();
    if (tid < 8) {
      const int b = tid;
      float cB = 1.f, cF = 1.f, Bv = 1.f;
      wU[b * 32 + 31] = lr[b * 32 + 31];
      wA[b * 32 + 31] = lr[b * 32 + 31];
      for (int t = 30; t >= 0; --t) {
        cB = sb[b * 32 + t + 1] * cB;
        cF = sf[b * 32 + t + 1] * cF;
        Bv = cF + sb[b * 32 + t + 1] * Bv;
        wU[b * 32 + t] = lr[b * 32 + t] * cB;
        wA[b * 32 + t] = lr[b * 32 + t] * Bv;
      }
      float ft = 1.f;
      for (int t = 0; t < 32; ++t) ft *= sf[b * 32 + t];
      Ft[b] = ft;
    }
    return;
  }
  const int g = blockIdx.x;
  if (tid < 128) kRow[tid] = gKeys[(size_t)g * 128 + tid];
  else vRow[tid - 128] = gVals[(size_t)g * 128 + (tid - 128)];
  __syncthreads();
  denseW<128, 256, 1>(mw1, mb1, kRow, 0, actA, 0, 1, scr);
  ws_h1[(size_t)g * 256 + tid] = actA[tid];
  denseW<256, 256, 1>(mw2, mb2, actA, 0, actB, 0, 1, scr);
  ws_h2[(size_t)g * 256 + tid] = actB[tid];
  denseW<256, 128, 1>(mw3, mb3, actB, 0, d3R, 0, 0, scr);
  if (tid < 128) {
    const float d = (d3R[tid] - vRow[tid]) * (2.f / 128.f);
    d3R[tid] = d;
    ws_d3[(size_t)g * 128 + tid] = d;
  }
  __syncthreads();
  // d2 = relu'(h2) * (mw3 row j . d3)
  {
    const int j = tid;
    float acc = 0.f;
    for (int jc = 0; jc < 128; jc += 4) {
      const float4 w = *reinterpret_cast<const float4*>(&mw3[(size_t)j * 128 + jc]);
      acc = fmaf(w.x, d3R[jc + 0], acc);
      acc = fmaf(w.y, d3R[jc + 1], acc);
      acc = fmaf(w.z, d3R[jc + 2], acc);
      acc = fmaf(w.w, d3R[jc + 3], acc);
    }
    const float v = (actB[j] > 0.f) ? acc : 0.f;
    d2R[j] = v;
    ws_d2[(size_t)g * 256 + j] = v;
  }
  __syncthreads();
  // d1 = relu'(h1) * (mw2 row j . d2)
  {
    const int j = tid;
    float acc = 0.f;
    for (int jc = 0; jc < 256; jc += 4) {
      const float4 w = *reinterpret_cast<const float4*>(&mw2[(size_t)j * 256 + jc]);
      acc = fmaf(w.x, d2R[jc + 0], acc);
      acc = fmaf(w.y, d2R[jc + 1], acc);
      acc = fmaf(w.z, d2R[jc + 2], acc);
      acc = fmaf(w.w, d2R[jc + 3], acc);
    }
    ws_d1[(size_t)g * 256 + j] = (actA[j] > 0.f) ? acc : 0.f;
  }
}

// ================= kW: outer products + bias + final =================
DEV void outer_body(const float* __restrict__ L, int Lld,
                    const float* __restrict__ D, int Dld,
                    const float* __restrict__ P,
                    const float* __restrict__ wA, const float* __restrict__ wU,
                    const float* __restrict__ Ftot,
                    float* __restrict__ out, size_t regionOff, int J,
                    int b, int i0, float* __restrict__ wAk, float* __restrict__ wUk)
{
  const int tid = threadIdx.x;
  for (int idx = tid; idx < 1024; idx += 256) {
    const int t = idx >> 5, ii = idx & 31;
    const float kv = L[(size_t)(b * 32 + t) * Lld + i0 + ii];
    wAk[t * 33 + ii] = wA[b * 32 + t] * kv;
    wUk[t * 33 + ii] = wU[b * 32 + t] * kv;
  }
  __syncthreads();
  const int j = (J == 256) ? tid : (tid & 127);
  const int g2 = (J == 256) ? 0 : (tid >> 7);
  const int span = (J == 256) ? 32 : 16;
  const int iBeg = g2 * span;
  float dv[32];
#pragma unroll
  for (int t = 0; t < 32; ++t) dv[t] = D[(size_t)(b * 32 + t) * Dld + j];
  const float ft = Ftot[b];
  float* ob = out + 1 + (size_t)b * (2 * W_TOT);
  for (int ii = iBeg; ii < iBeg + span; ++ii) {
    float aA = 0.f, aU = 0.f;
#pragma unroll
    for (int t = 0; t < 32; ++t) {
      aA = fmaf(wAk[t * 33 + ii], dv[t], aA);
      aU = fmaf(wUk[t * 33 + ii], dv[t], aU);
    }
    const int i = i0 + ii;
    const size_t w = regionOff + (size_t)i * J + j;
    ob[w] = ft * P[(size_t)i * J + j] - aA;
    ob[W_TOT + w] = aU;
  }
}

__global__ __launch_bounds__(256) void kW(
    const float* __restrict__ keys, const float* __restrict__ h1,
    const float* __restrict__ h2, const float* __restrict__ d1,
    const float* __restrict__ d2, const float* __restrict__ d3,
    const float* __restrict__ mw1, const float* __restrict__ mb1,
    const float* __restrict__ mw2, const float* __restrict__ mb2,
    const float* __restrict__ mw3, const float* __restrict__ mb3,
    const float* __restrict__ wA, const float* __restrict__ wU,
    const float* __restrict__ Ft, const float* __restrict__ lossPart,
    float* __restrict__ out)
{
  __shared__ float wAk[32 * 33], wUk[32 * 33];
  __shared__ float red[4];
  const int bid = blockIdx.x;
  const int tid = threadIdx.x;
  if (bid < 32) {
    outer_body(keys, 128, d1, 256, mw1, wA, wU, Ft, out, OFF_W1, 256,
               bid >> 2, (bid & 3) * 32, wAk, wUk);
  } else if (bid < 96) {
    const int x = bid - 32;
    outer_body(h1, 256, d2, 256, mw2, wA, wU, Ft, out, OFF_W2, 256,
               x >> 3, (x & 7) * 32, wAk, wUk);
  } else if (bid < 160) {
    const int x = bid - 96;
    outer_body(h2, 256, d3, 128, mw3, wA, wU, Ft, out, OFF_W3, 128,
               x >> 3, (x & 7) * 32, wAk, wUk);
  } else if (bid < 168) {
    const int b = bid - 160;
    const float ft = Ft[b];
    float* ob = out + 1 + (size_t)b * (2 * W_TOT);
    for (int idx = tid; idx < 640; idx += 256) {
      const float* D; int ld, j; size_t off; float pv;
      if (idx < 256)      { D = d1; ld = 256; j = idx;       off = OFF_B1; pv = mb1[j]; }
      else if (idx < 512) { D = d2; ld = 256; j = idx - 256; off = OFF_B2; pv = mb2[j]; }
      else                { D = d3; ld = 128; j = idx - 512; off = OFF_B3; pv = mb3[j]; }
      float aA = 0.f, aU = 0.f;
#pragma unroll
      for (int t = 0; t < 32; ++t) {
        const float dv = D[(size_t)(b * 32 + t) * ld + j];
        aA = fmaf(wA[b * 32 + t], dv, aA);
        aU = fmaf(wU[b * 32 + t], dv, aU);
      }
      ob[off + j] = ft * pv - aA;
      ob[W_TOT + off + j] = aU;
    }
  } else {
    const int c = tid >> 6, l = tid & 63;
    float v = lossPart[c * 256 + l] + lossPart[c * 256 + 64 + l] +
              lossPart[c * 256 + 128 + l] + lossPart[c * 256 + 192 + l];
#pragma unroll
    for (int s = 32; s > 0; s >>= 1) v += __shfl_xor(v, s);
    if (l == 0) red[c] = v;
    __syncthreads();
    if (tid == 0) {
      const float i1 = 1.f / (256.f * 512.f);
      const float i2 = 1.f / (256.f * 128.f);
      out[0] = red[0] * i1 + 2.f * red[1] * i2 + red[2] * i2 + red[3] * i1;
    }
  }
}

// ================= launch =================
extern "C" void kernel_launch(void* const* d_in, const int* in_sizes, int n_in,
                              void* d_out, int out_size, void* d_ws, size_t ws_size,
                              hipStream_t stream)
{
  const float* sensory = (const float*)d_in[0];
  const float* actions = (const float*)d_in[1];
  const float* enc_w = (const float*)d_in[2];
  const float* dec_w = (const float*)d_in[3];
  const float* pi_w1 = (const float*)d_in[4];
  const float* pi_b1 = (const float*)d_in[5];
  const float* pi_w2 = (const float*)d_in[6];
  const float* pi_b2 = (const float*)d_in[7];
  const float* pi_w3 = (const float*)d_in[8];
  const float* pi_b3 = (const float*)d_in[9];
  const float* rinit = (const float*)d_in[10];
  const float* wq = (const float*)d_in[11];
  const float* wk = (const float*)d_in[12];
  const float* wv = (const float*)d_in[13];
  const float* w_hp = (const float*)d_in[14];
  const float* mw1 = (const float*)d_in[15]; const float* mb1 = (const float*)d_in[16];
  const float* mw2 = (const float*)d_in[17]; const float* mb2 = (const float*)d_in[18];
  const float* mw3 = (const float*)d_in[19]; const float* mb3 = (const float*)d_in[20];
  const float* ow1 = (const float*)d_in[21]; const float* ob1 = (const float*)d_in[22];
  const float* ow2 = (const float*)d_in[23]; const float* ob2 = (const float*)d_in[24];
  const float* ow3 = (const float*)d_in[25]; const float* ob3 = (const float*)d_in[26];
  const float* vw1 = (const float*)d_in[27]; const float* vb1 = (const float*)d_in[28];
  const float* vw2 = (const float*)d_in[29]; const float* vb2 = (const float*)d_in[30];
  const float* vw3 = (const float*)d_in[31]; const float* vb3 = (const float*)d_in[32];
  const float* ir  = (const float*)d_in[33];

  float* ws  = (float*)d_ws;
  float* out = (float*)d_out;

  float* lossP = ws + P_LOSS;
  float* wA = ws + P_WA; float* wU = ws + P_WU; float* Ft = ws + P_FT;
  float* hp = ws + P_HP;
  float* h2pi = ws + P_H2PI;
  float* enc = ws + P_ENC;
  float* dgs = ws + P_DGS;
  float* inf = ws + P_INF;
  float* keys = ws + P_KEYS;
  float* vals = ws + P_VALS;
  float* d3s = ws + P_D3;
  float* h1s = ws + P_H1;
  float* h2s = ws + P_H2;
  float* d1s = ws + P_D1;
  float* d2s = ws + P_D2;
  float* structural = ws + P_STRUCT;
  float* trans = ws + P_TRANS;

  hipLaunchKernelGGL(k_pi_h2, dim3(256), dim3(128), 0, stream,
                     actions, pi_w1, pi_b1, pi_w2, pi_b2, h2pi);
  hipLaunchKernelGGL(k_pi_trans, dim3(512), dim3(256), 0, stream,
                     h2pi, pi_w3, pi_b3, trans);
  hipLaunchKernelGGL(k_rnn, dim3(8), dim3(1024), 0, stream, trans, rinit, structural);
  hipLaunchKernelGGL(kA, dim3(256), dim3(512), 0, stream,
                     sensory, structural, enc_w, wq, dec_w,
                     mw1, mb1, mw2, mb2, mw3, mb3,
                     ow1, ob1, ow2, ob2, ow3, ob3,
                     enc, dgs, lossP);
  hipLaunchKernelGGL(kB, dim3(256), dim3(512), 0, stream,
                     enc, dgs, wq,
                     mw1, mb1, mw2, mb2, mw3, mb3,
                     ow1, ob1, ow2, ob2, ow3, ob3,
                     vw1, vb1, vw2, vb2, vw3, vb3,
                     ir, inf, lossP);
  hipLaunchKernelGGL(kC, dim3(256), dim3(512), 0, stream,
                     sensory, enc, inf, wq, dec_w,
                     mw1, mb1, mw2, mb2, mw3, mb3,
                     ow1, ob1, ow2, ob2, ow3, ob3,
                     wk, wv, w_hp, keys, vals, hp, lossP);
  hipLaunchKernelGGL(kD, dim3(257), dim3(256), 0, stream,
                     keys, vals, hp, mw1, mb1, mw2, mb2, mw3, mb3,
                     h1s, h2s, d1s, d2s, d3s, wA, wU, Ft);
  hipLaunchKernelGGL(kW, dim3(169), dim3(256), 0, stream,
                     keys, h1s, h2s, d1s, d2s, d3s,
                     mw1, mb1, mw2, mb2, mw3, mb3,
                     wA, wU, Ft, lossP, out);
}